// Round 6
// baseline (8593.610 us; speedup 1.0000x reference)
//
#include <hip/hip_runtime.h>

#define N_PTS 16384
#define M_CTR 4096
#define K_NBR 64
#define F_OUT 128
#define CAP   256
#define FS    68
#define NCELL 4096   // 16x16x16 Morton cells
#define NBKT  512    // 16384/32 fixed 32-point buckets

// Exact (bitwise, no-contract) squared distance matching numpy f32:
// ((dx*dx + dy*dy) + dz*dz), each op round-to-nearest.
__device__ __forceinline__ float d2_exact(float ax, float ay, float az,
                                          float bx, float by, float bz) {
  float dx = __fsub_rn(ax, bx);
  float dy = __fsub_rn(ay, by);
  float dz = __fsub_rn(az, bz);
  return __fadd_rn(__fadd_rn(__fmul_rn(dx, dx), __fmul_rn(dy, dy)),
                   __fmul_rn(dz, dz));
}

// ---- wave64 max of a packed u64 key via DPP (row_shr 1/2/4/8 then
// row_bcast15 rows{1,3} + row_bcast31 rows{2,3}); lane 63 holds the max;
// readlane -> uniform. Step pattern verified in prior rounds (absmax 0).
__device__ __forceinline__ unsigned long long wave_max_u64(unsigned long long v) {
  int lo = (int)(unsigned)v;
  int hi = (int)(unsigned)(v >> 32);
#define DPPSTEP64(ctrl, rm)                                                    \
  {                                                                            \
    int tlo = __builtin_amdgcn_update_dpp(lo, lo, ctrl, rm, 0xf, false);       \
    int thi = __builtin_amdgcn_update_dpp(hi, hi, ctrl, rm, 0xf, false);       \
    unsigned long long cur =                                                   \
        ((unsigned long long)(unsigned)hi << 32) | (unsigned)lo;               \
    unsigned long long oth =                                                   \
        ((unsigned long long)(unsigned)thi << 32) | (unsigned)tlo;             \
    if (oth > cur) { lo = tlo; hi = thi; }                                     \
  }
  DPPSTEP64(0x111, 0xf) DPPSTEP64(0x112, 0xf) DPPSTEP64(0x114, 0xf)
  DPPSTEP64(0x118, 0xf) DPPSTEP64(0x142, 0xa) DPPSTEP64(0x143, 0xc)
#undef DPPSTEP64
  const unsigned rlo = (unsigned)__builtin_amdgcn_readlane(lo, 63);
  const unsigned rhi = (unsigned)__builtin_amdgcn_readlane(hi, 63);
  return ((unsigned long long)rhi << 32) | rlo;
}

// 32-lane-group full-broadcast max for u64: 4 DPP row_ror steps (1,2,4,8
// within each 16-row; VALU pipe) + one shfl_xor(16) merging the two rows of
// each 32-group. Verified v18 (absmax 0).
__device__ __forceinline__ unsigned long long bucket_bfly_max_u64(
    unsigned long long red) {
#define RORSTEP(ctrl)                                                          \
  {                                                                            \
    int lo = (int)(unsigned)red, hi = (int)(unsigned)(red >> 32);              \
    int tlo = __builtin_amdgcn_update_dpp(lo, lo, ctrl, 0xf, 0xf, false);      \
    int thi = __builtin_amdgcn_update_dpp(hi, hi, ctrl, 0xf, 0xf, false);      \
    unsigned long long o =                                                     \
        ((unsigned long long)(unsigned)thi << 32) | (unsigned)tlo;             \
    if (o > red) red = o;                                                      \
  }
  RORSTEP(0x121) RORSTEP(0x122) RORSTEP(0x124) RORSTEP(0x128)
#undef RORSTEP
  const unsigned olo = (unsigned)__shfl_xor((int)(unsigned)red, 16);
  const unsigned ohi = (unsigned)__shfl_xor((int)(unsigned)(red >> 32), 16);
  const unsigned long long o = ((unsigned long long)ohi << 32) | olo;
  return (o > red) ? o : red;
}

// ---------------------------------------------------------------------------
// Prep 1: global bbox of pos (single block) + zero the cell histogram.
// ---------------------------------------------------------------------------
__global__ void __launch_bounds__(1024) prep_bbox_kernel(const float* __restrict__ pos,
                                                         float* __restrict__ bbox,
                                                         int* __restrict__ hist) {
  const int tid = threadIdx.x;
  __shared__ float sred[6][16];
  float mn[3] = {INFINITY, INFINITY, INFINITY};
  float mx[3] = {-INFINITY, -INFINITY, -INFINITY};
  for (int p = tid; p < N_PTS; p += 1024) {
#pragma unroll
    for (int d = 0; d < 3; ++d) {
      float v = pos[3 * p + d];
      mn[d] = fminf(mn[d], v);
      mx[d] = fmaxf(mx[d], v);
    }
  }
#pragma unroll
  for (int off = 32; off > 0; off >>= 1) {
#pragma unroll
    for (int d = 0; d < 3; ++d) {
      mn[d] = fminf(mn[d], __shfl_xor(mn[d], off));
      mx[d] = fmaxf(mx[d], __shfl_xor(mx[d], off));
    }
  }
  if ((tid & 63) == 0) {
    const int w = tid >> 6;
#pragma unroll
    for (int d = 0; d < 3; ++d) { sred[d][w] = mn[d]; sred[3 + d][w] = mx[d]; }
  }
  __syncthreads();
  if (tid == 0) {
#pragma unroll
    for (int d = 0; d < 3; ++d) {
      float a = sred[d][0], b = sred[3 + d][0];
      for (int w = 1; w < 16; ++w) { a = fminf(a, sred[d][w]); b = fmaxf(b, sred[3 + d][w]); }
      bbox[d] = a; bbox[3 + d] = b;
    }
  }
  for (int i = tid; i < NCELL; i += 1024) hist[i] = 0;
}

// ---------------------------------------------------------------------------
// Prep 2: Morton cell id per point + histogram.
// ---------------------------------------------------------------------------
__device__ __forceinline__ int spread4(int v) {
  return (v & 1) | ((v & 2) << 2) | ((v & 4) << 4) | ((v & 8) << 6);
}

__global__ void __launch_bounds__(256) prep_cell_kernel(const float* __restrict__ pos,
                                                        const float* __restrict__ bbox,
                                                        int* __restrict__ cellid,
                                                        int* __restrict__ hist) {
  const int p = blockIdx.x * 256 + threadIdx.x;
  const float x = pos[3 * p], y = pos[3 * p + 1], z = pos[3 * p + 2];
  const float x0 = bbox[0], y0 = bbox[1], z0 = bbox[2];
  const float sx = 16.0f / fmaxf(bbox[3] - x0, 1e-20f);
  const float sy = 16.0f / fmaxf(bbox[4] - y0, 1e-20f);
  const float sz = 16.0f / fmaxf(bbox[5] - z0, 1e-20f);
  int cx = min(15, (int)((x - x0) * sx));
  int cy = min(15, (int)((y - y0) * sy));
  int cz = min(15, (int)((z - z0) * sz));
  const int c = spread4(cx) | (spread4(cy) << 1) | (spread4(cz) << 2);
  cellid[p] = c;
  atomicAdd(&hist[c], 1);
}

// ---------------------------------------------------------------------------
// Prep 3: exclusive scan of 4096 cell counts -> scatter cursors.
// ---------------------------------------------------------------------------
__global__ void __launch_bounds__(1024) prep_scan_kernel(const int* __restrict__ hist,
                                                         int* __restrict__ cursor) {
  __shared__ int tsum[1024];
  const int t = threadIdx.x;
  const int v0 = hist[4 * t + 0], v1 = hist[4 * t + 1];
  const int v2 = hist[4 * t + 2], v3 = hist[4 * t + 3];
  const int s = v0 + v1 + v2 + v3;
  int acc = s;
  tsum[t] = acc;
  __syncthreads();
  for (int off = 1; off < 1024; off <<= 1) {
    int add = (t >= off) ? tsum[t - off] : 0;
    __syncthreads();
    acc += add;
    tsum[t] = acc;
    __syncthreads();
  }
  int base = acc - s;  // exclusive
  cursor[4 * t + 0] = base;
  cursor[4 * t + 1] = base + v0;
  cursor[4 * t + 2] = base + v0 + v1;
  cursor[4 * t + 3] = base + v0 + v1 + v2;
}

// ---------------------------------------------------------------------------
// Prep 4: scatter to Morton-sorted packed SoA: gxyz[dst] = (x,y,z,bits(orig)).
// ---------------------------------------------------------------------------
__global__ void __launch_bounds__(256) prep_scatter_kernel(const float* __restrict__ pos,
                                                           const int* __restrict__ cellid,
                                                           int* __restrict__ cursor,
                                                           float4* __restrict__ gxyz) {
  const int p = blockIdx.x * 256 + threadIdx.x;
  const int c = cellid[p];
  const int dst = atomicAdd(&cursor[c], 1);
  gxyz[dst] = make_float4(pos[3 * p + 0], pos[3 * p + 1], pos[3 * p + 2],
                          __int_as_float(p));
}

// ---------------------------------------------------------------------------
// Prep 5: per-bucket bbox. Bucket = fixed 32-point chunk of sorted order.
// One 64-thread block handles 2 buckets (shfl_xor within 32-lane halves).
// ---------------------------------------------------------------------------
__global__ void __launch_bounds__(64) prep_bktbox_kernel(const float4* __restrict__ gxyz,
                                                         float* __restrict__ gbox) {
  const int lane = threadIdx.x;
  const float4 q = gxyz[blockIdx.x * 64 + lane];
  float mnx = q.x, mxx = q.x, mny = q.y, mxy = q.y, mnz = q.z, mxz = q.z;
#pragma unroll
  for (int off = 16; off > 0; off >>= 1) {
    mnx = fminf(mnx, __shfl_xor(mnx, off)); mxx = fmaxf(mxx, __shfl_xor(mxx, off));
    mny = fminf(mny, __shfl_xor(mny, off)); mxy = fmaxf(mxy, __shfl_xor(mxy, off));
    mnz = fminf(mnz, __shfl_xor(mnz, off)); mxz = fmaxf(mxz, __shfl_xor(mxz, off));
  }
  if ((lane & 31) == 0) {
    const int b = blockIdx.x * 2 + (lane >> 5);
    gbox[b * 8 + 0] = mnx; gbox[b * 8 + 1] = mxx;
    gbox[b * 8 + 2] = mny; gbox[b * 8 + 3] = mxy;
    gbox[b * 8 + 4] = mnz; gbox[b * 8 + 5] = mxz;
    gbox[b * 8 + 6] = 0.0f; gbox[b * 8 + 7] = 0.0f;
  }
}

// ---------------------------------------------------------------------------
// FPS v19 = v18 (pairing, 5175us, absmax 0) restructured to cut replicated
// work: v18 profile showed ~2700 redundant wave-inst/round (Phase C + pair
// test on 8 waves) + a serial pair-test tail (2nd DPP chain + gxyz/s_md
// loads). Changes:
//  1) 256 threads (4 waves, 1/SIMD): thread owns buckets tid and tid+256.
//     Replication 8x -> 4x, smaller barrier spread; Phase B still covers a
//     typical round (<=512 flagged pts) in <=2 pipelined iterations.
//  2) Per-bucket TOP-2 cache: Phase B runs the 32-group butterfly twice
//     (full, then value-masked) giving (r1, r2); winner lane writes s_pk,
//     s_pk2(=r2), s_wxyz; the r2 lane writes s_wxyz2. Runner-up in Phase C
//     becomes R = max(m2cand, s_pk2[b1]) from registers + one LDS read --
//     the per-round gxyz/s_md tail loads are gone. Exact: 2nd-best point
//     overall = max(2nd-best bucket winner, 2nd-best within A's bucket);
//     pk uniqueness carries ties; caches are rewritten whenever the
//     bucket's md changes (same freshness invariant as s_pk).
// Pairing condition, prune, d2/fmin order: bitwise-identical to v18.
// ---------------------------------------------------------------------------
__global__ void __launch_bounds__(256) fps_bucket_kernel(
    const float* __restrict__ pos, const float4* __restrict__ gxyz,
    const float* __restrict__ gbox,
    int* __restrict__ idx_out, float* __restrict__ pos_s_out,
    float* __restrict__ batch_s_out) {
  __shared__ float s_md[N_PTS];               // 64 KB running min-dist
  __shared__ unsigned long long s_pk[NBKT];   // 4 KB per-bucket winner pk
  __shared__ unsigned long long s_pk2[NBKT];  // 4 KB per-bucket runner-up pk
  __shared__ float4 s_wxyz[NBKT];             // 8 KB winner coords
  __shared__ float4 s_wxyz2[NBKT];            // 8 KB runner-up coords
  __shared__ int s_wl[NBKT];                  // 2 KB worklist
  __shared__ int s_cnt[2];                    // parity worklist counters
  __shared__ int s_sidx[M_CTR];               // 16 KB selected centers
  const int tid = threadIdx.x;
  const int lane = tid & 63, wave = tid >> 6;
  const int bA = tid, bB = tid + 256;         // owned buckets

  // init
  for (int i = tid; i < N_PTS; i += 256) s_md[i] = INFINITY;
  const unsigned long long PKINF = ((unsigned long long)0x7f800000u << 32);
  for (int i = tid; i < NBKT; i += 256) { s_pk[i] = PKINF; s_pk2[i] = 0ULL; }
  // own-bucket bboxes in registers
  const float aX0 = gbox[bA * 8 + 0], aX1 = gbox[bA * 8 + 1];
  const float aY0 = gbox[bA * 8 + 2], aY1 = gbox[bA * 8 + 3];
  const float aZ0 = gbox[bA * 8 + 4], aZ1 = gbox[bA * 8 + 5];
  const float bX0 = gbox[bB * 8 + 0], bX1 = gbox[bB * 8 + 1];
  const float bY0 = gbox[bB * 8 + 2], bY1 = gbox[bB * 8 + 3];
  const float bZ0 = gbox[bB * 8 + 4], bZ1 = gbox[bB * 8 + 5];
  unsigned long long mpkA = PKINF, mpkB = PKINF;  // cached own-bucket pks
  if (tid < 2) s_cnt[tid] = 0;

  float cxA = pos[0], cyA = pos[1], czA = pos[2];
  int idA = 0;
  float cxB = 0.0f, cyB = 0.0f, czB = 0.0f;
  int idB = 0;
  bool dual = false;
  int t = 0, rc = 0;
  __syncthreads();

  while (true) {
    if (tid == 0) s_sidx[t] = idA;
    ++t;
    if (t >= M_CTR) break;
    if (dual) {
      if (tid == 0) s_sidx[t] = idB;
      ++t;
      if (t >= M_CTR) break;
    }
    const int par = rc & 1;
    ++rc;

    // ---- Phase A: prune (union of balls when dual) + compaction ----
    const float rMaxA = __uint_as_float((unsigned)(mpkA >> 32));
    const float rMaxB = __uint_as_float((unsigned)(mpkB >> 32));
    float d0, d1, d2v;
    d0 = fmaxf(fmaxf(aX0 - cxA, cxA - aX1), 0.0f);
    d1 = fmaxf(fmaxf(aY0 - cyA, cyA - aY1), 0.0f);
    d2v = fmaxf(fmaxf(aZ0 - czA, czA - aZ1), 0.0f);
    bool flagA = (d0 * d0 + d1 * d1 + d2v * d2v) * 0.99999f < rMaxA;
    d0 = fmaxf(fmaxf(bX0 - cxA, cxA - bX1), 0.0f);
    d1 = fmaxf(fmaxf(bY0 - cyA, cyA - bY1), 0.0f);
    d2v = fmaxf(fmaxf(bZ0 - czA, czA - bZ1), 0.0f);
    bool flagB = (d0 * d0 + d1 * d1 + d2v * d2v) * 0.99999f < rMaxB;
    if (dual) {
      d0 = fmaxf(fmaxf(aX0 - cxB, cxB - aX1), 0.0f);
      d1 = fmaxf(fmaxf(aY0 - cyB, cyB - aY1), 0.0f);
      d2v = fmaxf(fmaxf(aZ0 - czB, czB - aZ1), 0.0f);
      flagA = flagA || ((d0 * d0 + d1 * d1 + d2v * d2v) * 0.99999f < rMaxA);
      d0 = fmaxf(fmaxf(bX0 - cxB, cxB - bX1), 0.0f);
      d1 = fmaxf(fmaxf(bY0 - cyB, cyB - bY1), 0.0f);
      d2v = fmaxf(fmaxf(bZ0 - czB, czB - bZ1), 0.0f);
      flagB = flagB || ((d0 * d0 + d1 * d1 + d2v * d2v) * 0.99999f < rMaxB);
    }
    {
      const unsigned long long ball = __ballot(flagA);
      int base = 0;
      if (lane == 0) base = atomicAdd(&s_cnt[par], __popcll(ball));
      base = __builtin_amdgcn_readfirstlane(base);
      if (flagA) s_wl[base + __popcll(ball & ((1ull << lane) - 1ull))] = bA;
    }
    {
      const unsigned long long ball = __ballot(flagB);
      int base = 0;
      if (lane == 0) base = atomicAdd(&s_cnt[par], __popcll(ball));
      base = __builtin_amdgcn_readfirstlane(base);
      if (flagB) s_wl[base + __popcll(ball & ((1ull << lane) - 1ull))] = bB;
    }
    __syncthreads();  // bar1: worklist + count ready
    if (tid == 0) s_cnt[par ^ 1] = 0;  // reset other parity (ordered by bar2)

    // ---- Phase B: process flagged buckets at point granularity ----
    const int nf = s_cnt[par];
    const int total = nf << 5;
    for (int bi = 0; bi < total; bi += 256) {
      const int idx = bi + tid;
      if (idx < total) {  // 32-aligned groups are uniformly on/off
        const int b = s_wl[idx >> 5];
        const int p = (b << 5) | (idx & 31);
        const float4 q = gxyz[p];  // coalesced 512B per group, L1/L2 hit
        float nmd = fminf(s_md[p], d2_exact(q.x, q.y, q.z, cxA, cyA, czA));
        if (dual) nmd = fminf(nmd, d2_exact(q.x, q.y, q.z, cxB, cyB, czB));
        s_md[p] = nmd;
        const unsigned long long own =
            ((unsigned long long)__float_as_uint(nmd) << 32) |
            ((unsigned long long)(16383u - (unsigned)__float_as_int(q.w)) << 14) |
            (unsigned)p;
        const unsigned long long r1 = bucket_bfly_max_u64(own);
        const unsigned long long msk = (own == r1) ? 0ULL : own;
        const unsigned long long r2 = bucket_bfly_max_u64(msk);
        if (own == r1) {  // unique winner lane (pk embeds posn)
          s_pk[b] = r1;
          s_pk2[b] = r2;
          s_wxyz[b] = make_float4(q.x, q.y, q.z, 0.0f);
        }
        if (own == r2) {  // unique (r2 < r1; only consulted when meaningful)
          s_wxyz2[b] = make_float4(q.x, q.y, q.z, 0.0f);
        }
      }
    }
    __syncthreads();  // bar2: s_pk/s_pk2/s_wxyz/s_wxyz2/s_md fully updated

    // ---- Phase C: replicated global top-2 (registers + cached LDS) ----
    unsigned long long vv[8];
    unsigned long long loc = 0ULL;
#pragma unroll
    for (int k = 0; k < 8; ++k) {
      vv[k] = s_pk[(k << 6) | lane];
      if (vv[k] > loc) loc = vv[k];
    }
    const unsigned long long m1 = wave_max_u64(loc);
    idA = 16383 - (int)((m1 >> 14) & 16383u);
    const int posn1 = (int)(m1 & 16383u);
    const int b1 = posn1 >> 5;
    {
      const float4 cq = s_wxyz[b1];  // broadcast LDS read
      cxA = cq.x; cyA = cq.y; czA = cq.z;
    }
    // own-bucket cache refresh (wave-uniform branch; static vv indices)
    if (wave == 0)      { mpkA = vv[0]; mpkB = vv[4]; }
    else if (wave == 1) { mpkA = vv[1]; mpkB = vv[5]; }
    else if (wave == 2) { mpkA = vv[2]; mpkB = vv[6]; }
    else                { mpkA = vv[3]; mpkB = vv[7]; }
    // runner-up: 2nd over bucket winners (value-masked) vs 2nd within b1
    unsigned long long loc2 = 0ULL;
#pragma unroll
    for (int k = 0; k < 8; ++k) {
      const unsigned long long u = (vv[k] == m1) ? 0ULL : vv[k];
      if (u > loc2) loc2 = u;
    }
    unsigned long long Rpk = wave_max_u64(loc2);
    const unsigned long long pk2b1 = s_pk2[b1];
    if (pk2b1 > Rpk) Rpk = pk2b1;
    const unsigned hiR = (unsigned)(Rpk >> 32);
    const int posnR = (int)(Rpk & 16383u);
    float rx, ry, rz;
    if ((posnR >> 5) == b1) {  // wave-uniform branch
      const float4 w = s_wxyz2[b1];
      rx = w.x; ry = w.y; rz = w.z;
    } else {
      const float4 w = s_wxyz[posnR >> 5];
      rx = w.x; ry = w.y; rz = w.z;
    }
    const float dAR = d2_exact(rx, ry, rz, cxA, cyA, czA);
    dual = (hiR != 0u) && (dAR >= __uint_as_float(hiR));
    if (dual) {
      cxB = rx; cyB = ry; czB = rz;
      idB = 16383 - (int)((Rpk >> 14) & 16383u);
    }
  }
  __syncthreads();
  for (int i = tid; i < M_CTR; i += 256) {
    const int si = s_sidx[i];
    idx_out[i] = si;
    pos_s_out[3 * i + 0] = pos[3 * si + 0];  // exact gather == pos[idx]
    pos_s_out[3 * i + 1] = pos[3 * si + 1];
    pos_s_out[3 * i + 2] = pos[3 * si + 2];
    batch_s_out[i] = 0.0f;
  }
}

// ---------------------------------------------------------------------------
// Kernel 2: radius neighbors (unchanged).
// ---------------------------------------------------------------------------
__global__ void __launch_bounds__(256) nbr_kernel(const float* __restrict__ pos,
                                                  const int* __restrict__ idx,
                                                  int* __restrict__ nbr) {
  const int m = blockIdx.x, tid = threadIdx.x;
  __shared__ int s_cnt;
  __shared__ float s_d2[CAP];
  __shared__ int s_idx[CAP];
  if (tid == 0) s_cnt = 0;
  const int cen = idx[m];
  const float cx = pos[3 * cen + 0], cy = pos[3 * cen + 1], cz = pos[3 * cen + 2];
  __syncthreads();
  const float RR = 0.04f;  // f32(python 0.2*0.2)
  for (int i = 0; i < N_PTS / 256; ++i) {
    const int p = tid + 256 * i;
    float d2 = d2_exact(pos[3 * p], pos[3 * p + 1], pos[3 * p + 2], cx, cy, cz);
    if (d2 <= RR) {
      int slot = atomicAdd(&s_cnt, 1);
      if (slot < CAP) { s_d2[slot] = d2; s_idx[slot] = p; }
    }
  }
  __syncthreads();
  const int cnt = s_cnt;
  if (cnt <= K_NBR) {
    if (tid < K_NBR) nbr[m * K_NBR + tid] = (tid < cnt) ? s_idx[tid] : cen;
  } else {
    const int n = cnt < CAP ? cnt : CAP;
    if (tid >= n) { s_d2[tid] = INFINITY; s_idx[tid] = 0x7fffffff; }
    __syncthreads();
    for (int k = 2; k <= CAP; k <<= 1) {
      for (int j = k >> 1; j > 0; j >>= 1) {
        const int ixj = tid ^ j;
        if (ixj > tid) {
          float da = s_d2[tid], db = s_d2[ixj];
          int ia = s_idx[tid], ib = s_idx[ixj];
          bool gt = (da > db) || (da == db && ia > ib);
          bool asc = ((tid & k) == 0);
          if (gt == asc) {
            s_d2[tid] = db; s_d2[ixj] = da;
            s_idx[tid] = ib; s_idx[ixj] = ia;
          }
        }
        __syncthreads();
      }
    }
    if (tid < K_NBR) nbr[m * K_NBR + tid] = s_idx[tid];
  }
}

// ---------------------------------------------------------------------------
// Kernel 3: fused gather + 3-layer MLP + max aggregation (unchanged).
// ---------------------------------------------------------------------------
__device__ __forceinline__ void mlp_layer(const float (*__restrict__ A)[FS],
                                          const float (*__restrict__ W)[64],
                                          int K, int e0, int c0, float acc[4][4]) {
#pragma unroll
  for (int j = 0; j < 4; ++j)
#pragma unroll
    for (int i = 0; i < 4; ++i) acc[j][i] = W[67][c0 + i];  // bias row
#pragma unroll 4
  for (int k = 0; k < K; ++k) {
    const float4 w = *(const float4*)&W[k][c0];
    const float a0 = A[e0 + 0][k], a1 = A[e0 + 1][k];
    const float a2 = A[e0 + 2][k], a3 = A[e0 + 3][k];
    acc[0][0] = fmaf(a0, w.x, acc[0][0]); acc[0][1] = fmaf(a0, w.y, acc[0][1]);
    acc[0][2] = fmaf(a0, w.z, acc[0][2]); acc[0][3] = fmaf(a0, w.w, acc[0][3]);
    acc[1][0] = fmaf(a1, w.x, acc[1][0]); acc[1][1] = fmaf(a1, w.y, acc[1][1]);
    acc[1][2] = fmaf(a1, w.z, acc[1][2]); acc[1][3] = fmaf(a1, w.w, acc[1][3]);
    acc[2][0] = fmaf(a2, w.x, acc[2][0]); acc[2][1] = fmaf(a2, w.y, acc[2][1]);
    acc[2][2] = fmaf(a2, w.z, acc[2][2]); acc[2][3] = fmaf(a2, w.w, acc[2][3]);
    acc[3][0] = fmaf(a3, w.x, acc[3][0]); acc[3][1] = fmaf(a3, w.y, acc[3][1]);
    acc[3][2] = fmaf(a3, w.z, acc[3][2]); acc[3][3] = fmaf(a3, w.w, acc[3][3]);
  }
#pragma unroll
  for (int j = 0; j < 4; ++j)
#pragma unroll
    for (int i = 0; i < 4; ++i) acc[j][i] = fmaxf(acc[j][i], 0.0f);
}

__global__ void __launch_bounds__(512) mlp_kernel(
    const float* __restrict__ x, const float* __restrict__ pos,
    const int* __restrict__ nbr, const float* __restrict__ pos_s,
    const float* __restrict__ W1, const float* __restrict__ b1,
    const float* __restrict__ W2, const float* __restrict__ b2,
    const float* __restrict__ W3, const float* __restrict__ b3,
    float* __restrict__ out) {
  __shared__ float Fb[2][64][FS];
  __shared__ float Wb[FS][64];
  __shared__ float Pb[2][16][64];
  __shared__ int s_nbr[128];
  const int t = threadIdx.x;
  const int m0 = blockIdx.x * 2;

  if (t < 128) s_nbr[t] = nbr[m0 * K_NBR + t];
  __syncthreads();

  {
    const int ge = t >> 2, wch = ge >> 6, e = ge & 63, c16 = (t & 3) * 16;
    const int n = s_nbr[ge];
    const float4* src = (const float4*)(x + n * 64 + c16);
    float4* dst = (float4*)(&Fb[wch][e][c16]);
    dst[0] = src[0]; dst[1] = src[1]; dst[2] = src[2]; dst[3] = src[3];
  }
  if (t < 128) {
    const int wch = t >> 6, e = t & 63;
    const int n = s_nbr[t];
    const float cx = pos_s[(m0 + wch) * 3 + 0];
    const float cy = pos_s[(m0 + wch) * 3 + 1];
    const float cz = pos_s[(m0 + wch) * 3 + 2];
    Fb[wch][e][64] = pos[3 * n + 0] - cx;
    Fb[wch][e][65] = pos[3 * n + 1] - cy;
    Fb[wch][e][66] = pos[3 * n + 2] - cz;
    Fb[wch][e][67] = 0.0f;
  }
  for (int i = t; i < 67 * 64; i += 512) ((float*)Wb)[i] = W1[i];
  if (t < 64) Wb[67][t] = b1[t];
  __syncthreads();

  const int wch = t >> 8, tt = t & 255;
  const int e0 = (tt >> 4) << 2, c0 = (tt & 15) << 2;
  float acc[4][4];

  mlp_layer(Fb[wch], Wb, 67, e0, c0, acc);
  __syncthreads();
#pragma unroll
  for (int j = 0; j < 4; ++j)
#pragma unroll
    for (int i = 0; i < 4; ++i) Fb[wch][e0 + j][c0 + i] = acc[j][i];
  for (int i = t; i < 64 * 64; i += 512) ((float*)Wb)[i] = W2[i];
  if (t < 64) Wb[67][t] = b2[t];
  __syncthreads();

  mlp_layer(Fb[wch], Wb, 64, e0, c0, acc);
  __syncthreads();
#pragma unroll
  for (int j = 0; j < 4; ++j)
#pragma unroll
    for (int i = 0; i < 4; ++i) Fb[wch][e0 + j][c0 + i] = acc[j][i];

  for (int h = 0; h < 2; ++h) {
    for (int i = t; i < 64 * 64; i += 512)
      ((float*)Wb)[i] = W3[(i >> 6) * 128 + h * 64 + (i & 63)];
    if (t < 64) Wb[67][t] = b3[h * 64 + t];
    __syncthreads();
    mlp_layer(Fb[wch], Wb, 64, e0, c0, acc);
#pragma unroll
    for (int i = 0; i < 4; ++i) {
      float v = fmaxf(fmaxf(acc[0][i], acc[1][i]), fmaxf(acc[2][i], acc[3][i]));
      Pb[wch][tt >> 4][c0 + i] = v;
    }
    __syncthreads();
    if (tt < 64) {
      float v = Pb[wch][0][tt];
#pragma unroll
      for (int r = 1; r < 16; ++r) v = fmaxf(v, Pb[wch][r][tt]);
      out[(m0 + wch) * F_OUT + h * 64 + tt] = v;
    }
    __syncthreads();
  }
}

// ---------------------------------------------------------------------------
extern "C" void kernel_launch(void* const* d_in, const int* in_sizes, int n_in,
                              void* d_out, int out_size, void* d_ws, size_t ws_size,
                              hipStream_t stream) {
  const float* x   = (const float*)d_in[0];
  const float* pos = (const float*)d_in[1];
  const float* W1 = (const float*)d_in[3];
  const float* b1 = (const float*)d_in[4];
  const float* W2 = (const float*)d_in[5];
  const float* b2 = (const float*)d_in[6];
  const float* W3 = (const float*)d_in[7];
  const float* b3 = (const float*)d_in[8];

  float* out     = (float*)d_out;                 // [M,128]
  float* pos_s   = out + M_CTR * F_OUT;           // [M,3]
  float* batch_s = pos_s + M_CTR * 3;             // [M]

  // workspace layout (gxyz offset 16B-aligned)
  int*    idx    = (int*)d_ws;                    // 4096
  int*    nbr    = idx + M_CTR;                   // 4096*64
  float*  bbox   = (float*)(nbr + M_CTR * K_NBR); // 8
  int*    hist   = (int*)(bbox + 8);              // 4096
  int*    cursor = hist + NCELL;                  // 4096
  int*    cellid = cursor + NCELL;                // 16384
  float4* gxyz   = (float4*)(cellid + N_PTS);     // 16384 float4
  // gbox (512 buckets x 8 floats = 16 KB) aliases hist: hist is dead after
  // prep_scan, and prep_bktbox runs strictly after it on the same stream.
  float*  gbox   = (float*)hist;

  prep_bbox_kernel<<<1, 1024, 0, stream>>>(pos, bbox, hist);
  prep_cell_kernel<<<N_PTS / 256, 256, 0, stream>>>(pos, bbox, cellid, hist);
  prep_scan_kernel<<<1, 1024, 0, stream>>>(hist, cursor);
  prep_scatter_kernel<<<N_PTS / 256, 256, 0, stream>>>(pos, cellid, cursor, gxyz);
  prep_bktbox_kernel<<<NBKT / 2, 64, 0, stream>>>(gxyz, gbox);
  fps_bucket_kernel<<<1, 256, 0, stream>>>(pos, gxyz, gbox, idx, pos_s, batch_s);
  nbr_kernel<<<M_CTR, 256, 0, stream>>>(pos, idx, nbr);
  mlp_kernel<<<M_CTR / 2, 512, 0, stream>>>(x, pos, nbr, pos_s,
                                            W1, b1, W2, b2, W3, b3, out);
}

// Round 7
// 6263.743 us; speedup vs baseline: 1.3720x; 1.3720x over previous
//
#include <hip/hip_runtime.h>

#define N_PTS 16384
#define M_CTR 4096
#define K_NBR 64
#define F_OUT 128
#define CAP   256
#define FS    68
#define NCELL 4096   // 16x16x16 Morton cells
#define NBKT  512    // 16384/32 fixed 32-point buckets

// Exact (bitwise, no-contract) squared distance matching numpy f32:
// ((dx*dx + dy*dy) + dz*dz), each op round-to-nearest.
__device__ __forceinline__ float d2_exact(float ax, float ay, float az,
                                          float bx, float by, float bz) {
  float dx = __fsub_rn(ax, bx);
  float dy = __fsub_rn(ay, by);
  float dz = __fsub_rn(az, bz);
  return __fadd_rn(__fadd_rn(__fmul_rn(dx, dx), __fmul_rn(dy, dy)),
                   __fmul_rn(dz, dz));
}

// ---- wave64 max of a packed u64 key via DPP (row_shr 1/2/4/8 then
// row_bcast15 rows{1,3} + row_bcast31 rows{2,3}); lane 63 holds the max;
// readlane -> uniform. Step pattern verified in prior rounds (absmax 0).
__device__ __forceinline__ unsigned long long wave_max_u64(unsigned long long v) {
  int lo = (int)(unsigned)v;
  int hi = (int)(unsigned)(v >> 32);
#define DPPSTEP64(ctrl, rm)                                                    \
  {                                                                            \
    int tlo = __builtin_amdgcn_update_dpp(lo, lo, ctrl, rm, 0xf, false);       \
    int thi = __builtin_amdgcn_update_dpp(hi, hi, ctrl, rm, 0xf, false);       \
    unsigned long long cur =                                                   \
        ((unsigned long long)(unsigned)hi << 32) | (unsigned)lo;               \
    unsigned long long oth =                                                   \
        ((unsigned long long)(unsigned)thi << 32) | (unsigned)tlo;             \
    if (oth > cur) { lo = tlo; hi = thi; }                                     \
  }
  DPPSTEP64(0x111, 0xf) DPPSTEP64(0x112, 0xf) DPPSTEP64(0x114, 0xf)
  DPPSTEP64(0x118, 0xf) DPPSTEP64(0x142, 0xa) DPPSTEP64(0x143, 0xc)
#undef DPPSTEP64
  const unsigned rlo = (unsigned)__builtin_amdgcn_readlane(lo, 63);
  const unsigned rhi = (unsigned)__builtin_amdgcn_readlane(hi, 63);
  return ((unsigned long long)rhi << 32) | rlo;
}

// 32-lane-group full-broadcast max for u64: 4 DPP row_ror steps (1,2,4,8
// within each 16-row; VALU pipe) + one shfl_xor(16) merging the two rows of
// each 32-group. Verified v18 (absmax 0).
__device__ __forceinline__ unsigned long long bucket_bfly_max_u64(
    unsigned long long red) {
#define RORSTEP(ctrl)                                                          \
  {                                                                            \
    int lo = (int)(unsigned)red, hi = (int)(unsigned)(red >> 32);              \
    int tlo = __builtin_amdgcn_update_dpp(lo, lo, ctrl, 0xf, 0xf, false);      \
    int thi = __builtin_amdgcn_update_dpp(hi, hi, ctrl, 0xf, 0xf, false);      \
    unsigned long long o =                                                     \
        ((unsigned long long)(unsigned)thi << 32) | (unsigned)tlo;             \
    if (o > red) red = o;                                                      \
  }
  RORSTEP(0x121) RORSTEP(0x122) RORSTEP(0x124) RORSTEP(0x128)
#undef RORSTEP
  const unsigned olo = (unsigned)__shfl_xor((int)(unsigned)red, 16);
  const unsigned ohi = (unsigned)__shfl_xor((int)(unsigned)(red >> 32), 16);
  const unsigned long long o = ((unsigned long long)ohi << 32) | olo;
  return (o > red) ? o : red;
}

// ---------------------------------------------------------------------------
// Prep 1: global bbox of pos (single block) + zero the cell histogram.
// ---------------------------------------------------------------------------
__global__ void __launch_bounds__(1024) prep_bbox_kernel(const float* __restrict__ pos,
                                                         float* __restrict__ bbox,
                                                         int* __restrict__ hist) {
  const int tid = threadIdx.x;
  __shared__ float sred[6][16];
  float mn[3] = {INFINITY, INFINITY, INFINITY};
  float mx[3] = {-INFINITY, -INFINITY, -INFINITY};
  for (int p = tid; p < N_PTS; p += 1024) {
#pragma unroll
    for (int d = 0; d < 3; ++d) {
      float v = pos[3 * p + d];
      mn[d] = fminf(mn[d], v);
      mx[d] = fmaxf(mx[d], v);
    }
  }
#pragma unroll
  for (int off = 32; off > 0; off >>= 1) {
#pragma unroll
    for (int d = 0; d < 3; ++d) {
      mn[d] = fminf(mn[d], __shfl_xor(mn[d], off));
      mx[d] = fmaxf(mx[d], __shfl_xor(mx[d], off));
    }
  }
  if ((tid & 63) == 0) {
    const int w = tid >> 6;
#pragma unroll
    for (int d = 0; d < 3; ++d) { sred[d][w] = mn[d]; sred[3 + d][w] = mx[d]; }
  }
  __syncthreads();
  if (tid == 0) {
#pragma unroll
    for (int d = 0; d < 3; ++d) {
      float a = sred[d][0], b = sred[3 + d][0];
      for (int w = 1; w < 16; ++w) { a = fminf(a, sred[d][w]); b = fmaxf(b, sred[3 + d][w]); }
      bbox[d] = a; bbox[3 + d] = b;
    }
  }
  for (int i = tid; i < NCELL; i += 1024) hist[i] = 0;
}

// ---------------------------------------------------------------------------
// Prep 2: Morton cell id per point + histogram.
// ---------------------------------------------------------------------------
__device__ __forceinline__ int spread4(int v) {
  return (v & 1) | ((v & 2) << 2) | ((v & 4) << 4) | ((v & 8) << 6);
}

__global__ void __launch_bounds__(256) prep_cell_kernel(const float* __restrict__ pos,
                                                        const float* __restrict__ bbox,
                                                        int* __restrict__ cellid,
                                                        int* __restrict__ hist) {
  const int p = blockIdx.x * 256 + threadIdx.x;
  const float x = pos[3 * p], y = pos[3 * p + 1], z = pos[3 * p + 2];
  const float x0 = bbox[0], y0 = bbox[1], z0 = bbox[2];
  const float sx = 16.0f / fmaxf(bbox[3] - x0, 1e-20f);
  const float sy = 16.0f / fmaxf(bbox[4] - y0, 1e-20f);
  const float sz = 16.0f / fmaxf(bbox[5] - z0, 1e-20f);
  int cx = min(15, (int)((x - x0) * sx));
  int cy = min(15, (int)((y - y0) * sy));
  int cz = min(15, (int)((z - z0) * sz));
  const int c = spread4(cx) | (spread4(cy) << 1) | (spread4(cz) << 2);
  cellid[p] = c;
  atomicAdd(&hist[c], 1);
}

// ---------------------------------------------------------------------------
// Prep 3: exclusive scan of 4096 cell counts -> scatter cursors.
// ---------------------------------------------------------------------------
__global__ void __launch_bounds__(1024) prep_scan_kernel(const int* __restrict__ hist,
                                                         int* __restrict__ cursor) {
  __shared__ int tsum[1024];
  const int t = threadIdx.x;
  const int v0 = hist[4 * t + 0], v1 = hist[4 * t + 1];
  const int v2 = hist[4 * t + 2], v3 = hist[4 * t + 3];
  const int s = v0 + v1 + v2 + v3;
  int acc = s;
  tsum[t] = acc;
  __syncthreads();
  for (int off = 1; off < 1024; off <<= 1) {
    int add = (t >= off) ? tsum[t - off] : 0;
    __syncthreads();
    acc += add;
    tsum[t] = acc;
    __syncthreads();
  }
  int base = acc - s;  // exclusive
  cursor[4 * t + 0] = base;
  cursor[4 * t + 1] = base + v0;
  cursor[4 * t + 2] = base + v0 + v1;
  cursor[4 * t + 3] = base + v0 + v1 + v2;
}

// ---------------------------------------------------------------------------
// Prep 4: scatter to Morton-sorted packed SoA: gxyz[dst] = (x,y,z,bits(orig)).
// ---------------------------------------------------------------------------
__global__ void __launch_bounds__(256) prep_scatter_kernel(const float* __restrict__ pos,
                                                           const int* __restrict__ cellid,
                                                           int* __restrict__ cursor,
                                                           float4* __restrict__ gxyz) {
  const int p = blockIdx.x * 256 + threadIdx.x;
  const int c = cellid[p];
  const int dst = atomicAdd(&cursor[c], 1);
  gxyz[dst] = make_float4(pos[3 * p + 0], pos[3 * p + 1], pos[3 * p + 2],
                          __int_as_float(p));
}

// ---------------------------------------------------------------------------
// Prep 5: per-bucket bbox. Bucket = fixed 32-point chunk of sorted order.
// One 64-thread block handles 2 buckets (shfl_xor within 32-lane halves).
// ---------------------------------------------------------------------------
__global__ void __launch_bounds__(64) prep_bktbox_kernel(const float4* __restrict__ gxyz,
                                                         float* __restrict__ gbox) {
  const int lane = threadIdx.x;
  const float4 q = gxyz[blockIdx.x * 64 + lane];
  float mnx = q.x, mxx = q.x, mny = q.y, mxy = q.y, mnz = q.z, mxz = q.z;
#pragma unroll
  for (int off = 16; off > 0; off >>= 1) {
    mnx = fminf(mnx, __shfl_xor(mnx, off)); mxx = fmaxf(mxx, __shfl_xor(mxx, off));
    mny = fminf(mny, __shfl_xor(mny, off)); mxy = fmaxf(mxy, __shfl_xor(mxy, off));
    mnz = fminf(mnz, __shfl_xor(mnz, off)); mxz = fmaxf(mxz, __shfl_xor(mxz, off));
  }
  if ((lane & 31) == 0) {
    const int b = blockIdx.x * 2 + (lane >> 5);
    gbox[b * 8 + 0] = mnx; gbox[b * 8 + 1] = mxx;
    gbox[b * 8 + 2] = mny; gbox[b * 8 + 3] = mxy;
    gbox[b * 8 + 4] = mnz; gbox[b * 8 + 5] = mxz;
    gbox[b * 8 + 6] = 0.0f; gbox[b * 8 + 7] = 0.0f;
  }
}

// ---------------------------------------------------------------------------
// FPS v20 = v18 VERBATIM (512 threads, worklist, pairing; best measured
// 5175us, absmax 0) + per-bucket TOP-2 cache only. v19 proved the 256-thread
// change was the regression (latency hiding lost: VALUBusy 51%->29% CU-local);
// the cache itself was never isolated. Here it is isolated:
//  - Phase B runs the ror-butterfly twice (full -> r1; value-masked -> r2;
//    +~70cyc on the VALU pipe) and caches (s_pk2[b], s_wxyz2[b]).
//  - Phase C runner-up R = max(value-masked 2nd over the vv[8] registers,
//    s_pk2[b1]); coords from s_wxyz2/s_wxyz. The per-round serial-tail
//    gxyz[pp] (~200-400cyc) + s_md[pp] loads are GONE.
// Exact: 2nd-best point overall = max(2nd-best bucket winner, 2nd-best
// within A's bucket); pk uniqueness carries ties; caches rewritten whenever
// the bucket's md changes (same freshness invariant as s_pk). Acceptance
// test, prune, d2/fmin order: bitwise-identical to v18.
// ---------------------------------------------------------------------------
__global__ void __launch_bounds__(512) fps_bucket_kernel(
    const float* __restrict__ pos, const float4* __restrict__ gxyz,
    const float* __restrict__ gbox,
    int* __restrict__ idx_out, float* __restrict__ pos_s_out,
    float* __restrict__ batch_s_out) {
  __shared__ float s_md[N_PTS];               // 64 KB running min-dist
  __shared__ unsigned long long s_pk[NBKT];   // 4 KB per-bucket winner pk
  __shared__ unsigned long long s_pk2[NBKT];  // 4 KB per-bucket runner-up pk
  __shared__ float4 s_wxyz[NBKT];             // 8 KB winner coords
  __shared__ float4 s_wxyz2[NBKT];            // 8 KB runner-up coords
  __shared__ int s_wl[NBKT];                  // 2 KB worklist
  __shared__ int s_cnt[2];                    // parity worklist counters
  __shared__ int s_sidx[M_CTR];               // 16 KB selected centers
  const int tid = threadIdx.x;
  const int lane = tid & 63, wave = tid >> 6;

  // init
  for (int i = tid; i < N_PTS; i += 512) s_md[i] = INFINITY;
  const unsigned long long PKINF = ((unsigned long long)0x7f800000u << 32);
  s_pk[tid] = PKINF;
  s_pk2[tid] = 0ULL;
  // own-bucket bbox in registers (thread t owns bucket t)
  const float bx0 = gbox[tid * 8 + 0], bx1 = gbox[tid * 8 + 1];
  const float by0 = gbox[tid * 8 + 2], by1 = gbox[tid * 8 + 3];
  const float bz0 = gbox[tid * 8 + 4], bz1 = gbox[tid * 8 + 5];
  unsigned long long mpk = PKINF;
  if (tid < 2) s_cnt[tid] = 0;

  float cxA = pos[0], cyA = pos[1], czA = pos[2];
  int idA = 0;
  float cxB = 0.0f, cyB = 0.0f, czB = 0.0f;
  int idB = 0;
  bool dual = false;
  int t = 0, rc = 0;
  __syncthreads();

  while (true) {
    if (tid == 0) s_sidx[t] = idA;
    ++t;
    if (t >= M_CTR) break;
    if (dual) {
      if (tid == 0) s_sidx[t] = idB;
      ++t;
      if (t >= M_CTR) break;
    }
    const int par = rc & 1;
    ++rc;

    // ---- Phase A: prune (union of balls when dual) + compaction ----
    const float rMax = __uint_as_float((unsigned)(mpk >> 32));
    float dxl = fmaxf(fmaxf(bx0 - cxA, cxA - bx1), 0.0f);
    float dyl = fmaxf(fmaxf(by0 - cyA, cyA - by1), 0.0f);
    float dzl = fmaxf(fmaxf(bz0 - czA, czA - bz1), 0.0f);
    bool flag = (dxl * dxl + dyl * dyl + dzl * dzl) * 0.99999f < rMax;
    if (dual) {
      float ex = fmaxf(fmaxf(bx0 - cxB, cxB - bx1), 0.0f);
      float ey = fmaxf(fmaxf(by0 - cyB, cyB - by1), 0.0f);
      float ez = fmaxf(fmaxf(bz0 - czB, czB - bz1), 0.0f);
      flag = flag || ((ex * ex + ey * ey + ez * ez) * 0.99999f < rMax);
    }
    const unsigned long long ball = __ballot(flag);
    int base = 0;
    if (lane == 0) base = atomicAdd(&s_cnt[par], __popcll(ball));
    base = __builtin_amdgcn_readfirstlane(base);
    if (flag) {
      const int pre = __popcll(ball & ((1ull << lane) - 1ull));
      s_wl[base + pre] = tid;
    }
    __syncthreads();  // bar1: worklist + count ready
    if (tid == 0) s_cnt[par ^ 1] = 0;  // reset other parity (ordered by bar2)

    // ---- Phase B: process flagged buckets at point granularity ----
    const int nf = s_cnt[par];
    const int total = nf << 5;
    for (int bi = 0; bi < total; bi += 512) {
      const int idx = bi + tid;
      if (idx < total) {  // 32-aligned groups are uniformly on/off
        const int b = s_wl[idx >> 5];
        const int p = (b << 5) | (idx & 31);
        const float4 q = gxyz[p];  // coalesced 512B per group, L1/L2 hit
        float nmd = fminf(s_md[p], d2_exact(q.x, q.y, q.z, cxA, cyA, czA));
        if (dual) nmd = fminf(nmd, d2_exact(q.x, q.y, q.z, cxB, cyB, czB));
        s_md[p] = nmd;
        const unsigned long long own =
            ((unsigned long long)__float_as_uint(nmd) << 32) |
            ((unsigned long long)(16383u - (unsigned)__float_as_int(q.w)) << 14) |
            (unsigned)p;
        const unsigned long long r1 = bucket_bfly_max_u64(own);
        const unsigned long long msk = (own == r1) ? 0ULL : own;
        const unsigned long long r2 = bucket_bfly_max_u64(msk);
        if (own == r1) {  // unique winner lane (pk embeds posn)
          s_pk[b] = r1;
          s_pk2[b] = r2;
          s_wxyz[b] = make_float4(q.x, q.y, q.z, 0.0f);
        }
        if (own == r2) {  // unique (r2 < r1)
          s_wxyz2[b] = make_float4(q.x, q.y, q.z, 0.0f);
        }
      }
    }
    __syncthreads();  // bar2: s_pk/s_pk2/s_wxyz/s_wxyz2/s_md fully updated

    // ---- Phase C: replicated global argmax -> A ----
    unsigned long long vv[8];
    unsigned long long loc = 0ULL;
#pragma unroll
    for (int k = 0; k < 8; ++k) {
      const unsigned long long u = s_pk[(k << 6) | lane];
      vv[k] = u;
      if (k == wave) mpk = u;  // own bucket's cache for next Phase A
      if (u > loc) loc = u;
    }
    const unsigned long long m1 = wave_max_u64(loc);
    idA = 16383 - (int)((m1 >> 14) & 16383u);
    const int posn1 = (int)(m1 & 16383u);
    const int b1 = posn1 >> 5;
    {
      const float4 cq = s_wxyz[b1];  // broadcast LDS read
      cxA = cq.x; cyA = cq.y; czA = cq.z;
    }

    // ---- runner-up from caches (no gxyz/s_md tail loads) ----
    unsigned long long loc2 = 0ULL;
#pragma unroll
    for (int k = 0; k < 8; ++k) {
      const unsigned long long u = (vv[k] == m1) ? 0ULL : vv[k];  // value mask
      if (u > loc2) loc2 = u;
    }
    unsigned long long Rpk = wave_max_u64(loc2);
    const unsigned long long pk2b1 = s_pk2[b1];
    if (pk2b1 > Rpk) Rpk = pk2b1;
    const unsigned hiR = (unsigned)(Rpk >> 32);
    const int posnR = (int)(Rpk & 16383u);
    float rx, ry, rz;
    if ((posnR >> 5) == b1) {  // wave-uniform branch: R is b1's runner-up
      const float4 w = s_wxyz2[b1];
      rx = w.x; ry = w.y; rz = w.z;
    } else {
      const float4 w = s_wxyz[posnR >> 5];
      rx = w.x; ry = w.y; rz = w.z;
    }
    const float dAR = d2_exact(rx, ry, rz, cxA, cyA, czA);
    dual = (hiR != 0u) && (dAR >= __uint_as_float(hiR));
    if (dual) {
      cxB = rx; cyB = ry; czB = rz;
      idB = 16383 - (int)((Rpk >> 14) & 16383u);
    }
  }
  __syncthreads();
  for (int i = tid; i < M_CTR; i += 512) {
    const int si = s_sidx[i];
    idx_out[i] = si;
    pos_s_out[3 * i + 0] = pos[3 * si + 0];  // exact gather == pos[idx]
    pos_s_out[3 * i + 1] = pos[3 * si + 1];
    pos_s_out[3 * i + 2] = pos[3 * si + 2];
    batch_s_out[i] = 0.0f;
  }
}

// ---------------------------------------------------------------------------
// Kernel 2: radius neighbors (unchanged).
// ---------------------------------------------------------------------------
__global__ void __launch_bounds__(256) nbr_kernel(const float* __restrict__ pos,
                                                  const int* __restrict__ idx,
                                                  int* __restrict__ nbr) {
  const int m = blockIdx.x, tid = threadIdx.x;
  __shared__ int s_cnt;
  __shared__ float s_d2[CAP];
  __shared__ int s_idx[CAP];
  if (tid == 0) s_cnt = 0;
  const int cen = idx[m];
  const float cx = pos[3 * cen + 0], cy = pos[3 * cen + 1], cz = pos[3 * cen + 2];
  __syncthreads();
  const float RR = 0.04f;  // f32(python 0.2*0.2)
  for (int i = 0; i < N_PTS / 256; ++i) {
    const int p = tid + 256 * i;
    float d2 = d2_exact(pos[3 * p], pos[3 * p + 1], pos[3 * p + 2], cx, cy, cz);
    if (d2 <= RR) {
      int slot = atomicAdd(&s_cnt, 1);
      if (slot < CAP) { s_d2[slot] = d2; s_idx[slot] = p; }
    }
  }
  __syncthreads();
  const int cnt = s_cnt;
  if (cnt <= K_NBR) {
    if (tid < K_NBR) nbr[m * K_NBR + tid] = (tid < cnt) ? s_idx[tid] : cen;
  } else {
    const int n = cnt < CAP ? cnt : CAP;
    if (tid >= n) { s_d2[tid] = INFINITY; s_idx[tid] = 0x7fffffff; }
    __syncthreads();
    for (int k = 2; k <= CAP; k <<= 1) {
      for (int j = k >> 1; j > 0; j >>= 1) {
        const int ixj = tid ^ j;
        if (ixj > tid) {
          float da = s_d2[tid], db = s_d2[ixj];
          int ia = s_idx[tid], ib = s_idx[ixj];
          bool gt = (da > db) || (da == db && ia > ib);
          bool asc = ((tid & k) == 0);
          if (gt == asc) {
            s_d2[tid] = db; s_d2[ixj] = da;
            s_idx[tid] = ib; s_idx[ixj] = ia;
          }
        }
        __syncthreads();
      }
    }
    if (tid < K_NBR) nbr[m * K_NBR + tid] = s_idx[tid];
  }
}

// ---------------------------------------------------------------------------
// Kernel 3: fused gather + 3-layer MLP + max aggregation (unchanged).
// ---------------------------------------------------------------------------
__device__ __forceinline__ void mlp_layer(const float (*__restrict__ A)[FS],
                                          const float (*__restrict__ W)[64],
                                          int K, int e0, int c0, float acc[4][4]) {
#pragma unroll
  for (int j = 0; j < 4; ++j)
#pragma unroll
    for (int i = 0; i < 4; ++i) acc[j][i] = W[67][c0 + i];  // bias row
#pragma unroll 4
  for (int k = 0; k < K; ++k) {
    const float4 w = *(const float4*)&W[k][c0];
    const float a0 = A[e0 + 0][k], a1 = A[e0 + 1][k];
    const float a2 = A[e0 + 2][k], a3 = A[e0 + 3][k];
    acc[0][0] = fmaf(a0, w.x, acc[0][0]); acc[0][1] = fmaf(a0, w.y, acc[0][1]);
    acc[0][2] = fmaf(a0, w.z, acc[0][2]); acc[0][3] = fmaf(a0, w.w, acc[0][3]);
    acc[1][0] = fmaf(a1, w.x, acc[1][0]); acc[1][1] = fmaf(a1, w.y, acc[1][1]);
    acc[1][2] = fmaf(a1, w.z, acc[1][2]); acc[1][3] = fmaf(a1, w.w, acc[1][3]);
    acc[2][0] = fmaf(a2, w.x, acc[2][0]); acc[2][1] = fmaf(a2, w.y, acc[2][1]);
    acc[2][2] = fmaf(a2, w.z, acc[2][2]); acc[2][3] = fmaf(a2, w.w, acc[2][3]);
    acc[3][0] = fmaf(a3, w.x, acc[3][0]); acc[3][1] = fmaf(a3, w.y, acc[3][1]);
    acc[3][2] = fmaf(a3, w.z, acc[3][2]); acc[3][3] = fmaf(a3, w.w, acc[3][3]);
  }
#pragma unroll
  for (int j = 0; j < 4; ++j)
#pragma unroll
    for (int i = 0; i < 4; ++i) acc[j][i] = fmaxf(acc[j][i], 0.0f);
}

__global__ void __launch_bounds__(512) mlp_kernel(
    const float* __restrict__ x, const float* __restrict__ pos,
    const int* __restrict__ nbr, const float* __restrict__ pos_s,
    const float* __restrict__ W1, const float* __restrict__ b1,
    const float* __restrict__ W2, const float* __restrict__ b2,
    const float* __restrict__ W3, const float* __restrict__ b3,
    float* __restrict__ out) {
  __shared__ float Fb[2][64][FS];
  __shared__ float Wb[FS][64];
  __shared__ float Pb[2][16][64];
  __shared__ int s_nbr[128];
  const int t = threadIdx.x;
  const int m0 = blockIdx.x * 2;

  if (t < 128) s_nbr[t] = nbr[m0 * K_NBR + t];
  __syncthreads();

  {
    const int ge = t >> 2, wch = ge >> 6, e = ge & 63, c16 = (t & 3) * 16;
    const int n = s_nbr[ge];
    const float4* src = (const float4*)(x + n * 64 + c16);
    float4* dst = (float4*)(&Fb[wch][e][c16]);
    dst[0] = src[0]; dst[1] = src[1]; dst[2] = src[2]; dst[3] = src[3];
  }
  if (t < 128) {
    const int wch = t >> 6, e = t & 63;
    const int n = s_nbr[t];
    const float cx = pos_s[(m0 + wch) * 3 + 0];
    const float cy = pos_s[(m0 + wch) * 3 + 1];
    const float cz = pos_s[(m0 + wch) * 3 + 2];
    Fb[wch][e][64] = pos[3 * n + 0] - cx;
    Fb[wch][e][65] = pos[3 * n + 1] - cy;
    Fb[wch][e][66] = pos[3 * n + 2] - cz;
    Fb[wch][e][67] = 0.0f;
  }
  for (int i = t; i < 67 * 64; i += 512) ((float*)Wb)[i] = W1[i];
  if (t < 64) Wb[67][t] = b1[t];
  __syncthreads();

  const int wch = t >> 8, tt = t & 255;
  const int e0 = (tt >> 4) << 2, c0 = (tt & 15) << 2;
  float acc[4][4];

  mlp_layer(Fb[wch], Wb, 67, e0, c0, acc);
  __syncthreads();
#pragma unroll
  for (int j = 0; j < 4; ++j)
#pragma unroll
    for (int i = 0; i < 4; ++i) Fb[wch][e0 + j][c0 + i] = acc[j][i];
  for (int i = t; i < 64 * 64; i += 512) ((float*)Wb)[i] = W2[i];
  if (t < 64) Wb[67][t] = b2[t];
  __syncthreads();

  mlp_layer(Fb[wch], Wb, 64, e0, c0, acc);
  __syncthreads();
#pragma unroll
  for (int j = 0; j < 4; ++j)
#pragma unroll
    for (int i = 0; i < 4; ++i) Fb[wch][e0 + j][c0 + i] = acc[j][i];

  for (int h = 0; h < 2; ++h) {
    for (int i = t; i < 64 * 64; i += 512)
      ((float*)Wb)[i] = W3[(i >> 6) * 128 + h * 64 + (i & 63)];
    if (t < 64) Wb[67][t] = b3[h * 64 + t];
    __syncthreads();
    mlp_layer(Fb[wch], Wb, 64, e0, c0, acc);
#pragma unroll
    for (int i = 0; i < 4; ++i) {
      float v = fmaxf(fmaxf(acc[0][i], acc[1][i]), fmaxf(acc[2][i], acc[3][i]));
      Pb[wch][tt >> 4][c0 + i] = v;
    }
    __syncthreads();
    if (tt < 64) {
      float v = Pb[wch][0][tt];
#pragma unroll
      for (int r = 1; r < 16; ++r) v = fmaxf(v, Pb[wch][r][tt]);
      out[(m0 + wch) * F_OUT + h * 64 + tt] = v;
    }
    __syncthreads();
  }
}

// ---------------------------------------------------------------------------
extern "C" void kernel_launch(void* const* d_in, const int* in_sizes, int n_in,
                              void* d_out, int out_size, void* d_ws, size_t ws_size,
                              hipStream_t stream) {
  const float* x   = (const float*)d_in[0];
  const float* pos = (const float*)d_in[1];
  const float* W1 = (const float*)d_in[3];
  const float* b1 = (const float*)d_in[4];
  const float* W2 = (const float*)d_in[5];
  const float* b2 = (const float*)d_in[6];
  const float* W3 = (const float*)d_in[7];
  const float* b3 = (const float*)d_in[8];

  float* out     = (float*)d_out;                 // [M,128]
  float* pos_s   = out + M_CTR * F_OUT;           // [M,3]
  float* batch_s = pos_s + M_CTR * 3;             // [M]

  // workspace layout (gxyz offset 16B-aligned)
  int*    idx    = (int*)d_ws;                    // 4096
  int*    nbr    = idx + M_CTR;                   // 4096*64
  float*  bbox   = (float*)(nbr + M_CTR * K_NBR); // 8
  int*    hist   = (int*)(bbox + 8);              // 4096
  int*    cursor = hist + NCELL;                  // 4096
  int*    cellid = cursor + NCELL;                // 16384
  float4* gxyz   = (float4*)(cellid + N_PTS);     // 16384 float4
  // gbox (512 buckets x 8 floats = 16 KB) aliases hist: hist is dead after
  // prep_scan, and prep_bktbox runs strictly after it on the same stream.
  float*  gbox   = (float*)hist;

  prep_bbox_kernel<<<1, 1024, 0, stream>>>(pos, bbox, hist);
  prep_cell_kernel<<<N_PTS / 256, 256, 0, stream>>>(pos, bbox, cellid, hist);
  prep_scan_kernel<<<1, 1024, 0, stream>>>(hist, cursor);
  prep_scatter_kernel<<<N_PTS / 256, 256, 0, stream>>>(pos, cellid, cursor, gxyz);
  prep_bktbox_kernel<<<NBKT / 2, 64, 0, stream>>>(gxyz, gbox);
  fps_bucket_kernel<<<1, 512, 0, stream>>>(pos, gxyz, gbox, idx, pos_s, batch_s);
  nbr_kernel<<<M_CTR, 256, 0, stream>>>(pos, idx, nbr);
  mlp_kernel<<<M_CTR / 2, 512, 0, stream>>>(x, pos, nbr, pos_s,
                                            W1, b1, W2, b2, W3, b3, out);
}

// Round 8
// 5357.639 us; speedup vs baseline: 1.6040x; 1.1691x over previous
//
#include <hip/hip_runtime.h>

#define N_PTS 16384
#define M_CTR 4096
#define K_NBR 64
#define F_OUT 128
#define CAP   256
#define FS    68
#define NCELL 4096   // 16x16x16 Morton cells
#define NBKT  512    // 16384/32 fixed 32-point buckets

// Exact (bitwise, no-contract) squared distance matching numpy f32:
// ((dx*dx + dy*dy) + dz*dz), each op round-to-nearest.
__device__ __forceinline__ float d2_exact(float ax, float ay, float az,
                                          float bx, float by, float bz) {
  float dx = __fsub_rn(ax, bx);
  float dy = __fsub_rn(ay, by);
  float dz = __fsub_rn(az, bz);
  return __fadd_rn(__fadd_rn(__fmul_rn(dx, dx), __fmul_rn(dy, dy)),
                   __fmul_rn(dz, dz));
}

__device__ __forceinline__ float readlane_f(float v, int ln) {
  return __int_as_float(__builtin_amdgcn_readlane(__float_as_int(v), ln));
}

// ---- wave64 max of a packed u64 key via DPP (row_shr 1/2/4/8 then
// row_bcast15 rows{1,3} + row_bcast31 rows{2,3}); lane 63 holds the max;
// readlane -> uniform. Step pattern verified in prior rounds (absmax 0).
__device__ __forceinline__ unsigned long long wave_max_u64(unsigned long long v) {
  int lo = (int)(unsigned)v;
  int hi = (int)(unsigned)(v >> 32);
#define DPPSTEP64(ctrl, rm)                                                    \
  {                                                                            \
    int tlo = __builtin_amdgcn_update_dpp(lo, lo, ctrl, rm, 0xf, false);       \
    int thi = __builtin_amdgcn_update_dpp(hi, hi, ctrl, rm, 0xf, false);       \
    unsigned long long cur =                                                   \
        ((unsigned long long)(unsigned)hi << 32) | (unsigned)lo;               \
    unsigned long long oth =                                                   \
        ((unsigned long long)(unsigned)thi << 32) | (unsigned)tlo;             \
    if (oth > cur) { lo = tlo; hi = thi; }                                     \
  }
  DPPSTEP64(0x111, 0xf) DPPSTEP64(0x112, 0xf) DPPSTEP64(0x114, 0xf)
  DPPSTEP64(0x118, 0xf) DPPSTEP64(0x142, 0xa) DPPSTEP64(0x143, 0xc)
#undef DPPSTEP64
  const unsigned rlo = (unsigned)__builtin_amdgcn_readlane(lo, 63);
  const unsigned rhi = (unsigned)__builtin_amdgcn_readlane(hi, 63);
  return ((unsigned long long)rhi << 32) | rlo;
}

// 32-lane-group full-broadcast max for u64: 4 DPP row_ror steps (1,2,4,8
// within each 16-row; VALU pipe) + one shfl_xor(16) merging the two rows of
// each 32-group. Max is order-invariant. Verified v18 (absmax 0).
__device__ __forceinline__ unsigned long long bucket_bfly_max_u64(
    unsigned long long red) {
#define RORSTEP(ctrl)                                                          \
  {                                                                            \
    int lo = (int)(unsigned)red, hi = (int)(unsigned)(red >> 32);              \
    int tlo = __builtin_amdgcn_update_dpp(lo, lo, ctrl, 0xf, 0xf, false);      \
    int thi = __builtin_amdgcn_update_dpp(hi, hi, ctrl, 0xf, 0xf, false);      \
    unsigned long long o =                                                     \
        ((unsigned long long)(unsigned)thi << 32) | (unsigned)tlo;             \
    if (o > red) red = o;                                                      \
  }
  RORSTEP(0x121) RORSTEP(0x122) RORSTEP(0x124) RORSTEP(0x128)
#undef RORSTEP
  const unsigned olo = (unsigned)__shfl_xor((int)(unsigned)red, 16);
  const unsigned ohi = (unsigned)__shfl_xor((int)(unsigned)(red >> 32), 16);
  const unsigned long long o = ((unsigned long long)ohi << 32) | olo;
  return (o > red) ? o : red;
}

// ---------------------------------------------------------------------------
// Prep 1: global bbox of pos (single block) + zero the cell histogram.
// ---------------------------------------------------------------------------
__global__ void __launch_bounds__(1024) prep_bbox_kernel(const float* __restrict__ pos,
                                                         float* __restrict__ bbox,
                                                         int* __restrict__ hist) {
  const int tid = threadIdx.x;
  __shared__ float sred[6][16];
  float mn[3] = {INFINITY, INFINITY, INFINITY};
  float mx[3] = {-INFINITY, -INFINITY, -INFINITY};
  for (int p = tid; p < N_PTS; p += 1024) {
#pragma unroll
    for (int d = 0; d < 3; ++d) {
      float v = pos[3 * p + d];
      mn[d] = fminf(mn[d], v);
      mx[d] = fmaxf(mx[d], v);
    }
  }
#pragma unroll
  for (int off = 32; off > 0; off >>= 1) {
#pragma unroll
    for (int d = 0; d < 3; ++d) {
      mn[d] = fminf(mn[d], __shfl_xor(mn[d], off));
      mx[d] = fmaxf(mx[d], __shfl_xor(mx[d], off));
    }
  }
  if ((tid & 63) == 0) {
    const int w = tid >> 6;
#pragma unroll
    for (int d = 0; d < 3; ++d) { sred[d][w] = mn[d]; sred[3 + d][w] = mx[d]; }
  }
  __syncthreads();
  if (tid == 0) {
#pragma unroll
    for (int d = 0; d < 3; ++d) {
      float a = sred[d][0], b = sred[3 + d][0];
      for (int w = 1; w < 16; ++w) { a = fminf(a, sred[d][w]); b = fmaxf(b, sred[3 + d][w]); }
      bbox[d] = a; bbox[3 + d] = b;
    }
  }
  for (int i = tid; i < NCELL; i += 1024) hist[i] = 0;
}

// ---------------------------------------------------------------------------
// Prep 2: Morton cell id per point + histogram.
// ---------------------------------------------------------------------------
__device__ __forceinline__ int spread4(int v) {
  return (v & 1) | ((v & 2) << 2) | ((v & 4) << 4) | ((v & 8) << 6);
}

__global__ void __launch_bounds__(256) prep_cell_kernel(const float* __restrict__ pos,
                                                        const float* __restrict__ bbox,
                                                        int* __restrict__ cellid,
                                                        int* __restrict__ hist) {
  const int p = blockIdx.x * 256 + threadIdx.x;
  const float x = pos[3 * p], y = pos[3 * p + 1], z = pos[3 * p + 2];
  const float x0 = bbox[0], y0 = bbox[1], z0 = bbox[2];
  const float sx = 16.0f / fmaxf(bbox[3] - x0, 1e-20f);
  const float sy = 16.0f / fmaxf(bbox[4] - y0, 1e-20f);
  const float sz = 16.0f / fmaxf(bbox[5] - z0, 1e-20f);
  int cx = min(15, (int)((x - x0) * sx));
  int cy = min(15, (int)((y - y0) * sy));
  int cz = min(15, (int)((z - z0) * sz));
  const int c = spread4(cx) | (spread4(cy) << 1) | (spread4(cz) << 2);
  cellid[p] = c;
  atomicAdd(&hist[c], 1);
}

// ---------------------------------------------------------------------------
// Prep 3: exclusive scan of 4096 cell counts -> scatter cursors.
// ---------------------------------------------------------------------------
__global__ void __launch_bounds__(1024) prep_scan_kernel(const int* __restrict__ hist,
                                                         int* __restrict__ cursor) {
  __shared__ int tsum[1024];
  const int t = threadIdx.x;
  const int v0 = hist[4 * t + 0], v1 = hist[4 * t + 1];
  const int v2 = hist[4 * t + 2], v3 = hist[4 * t + 3];
  const int s = v0 + v1 + v2 + v3;
  int acc = s;
  tsum[t] = acc;
  __syncthreads();
  for (int off = 1; off < 1024; off <<= 1) {
    int add = (t >= off) ? tsum[t - off] : 0;
    __syncthreads();
    acc += add;
    tsum[t] = acc;
    __syncthreads();
  }
  int base = acc - s;  // exclusive
  cursor[4 * t + 0] = base;
  cursor[4 * t + 1] = base + v0;
  cursor[4 * t + 2] = base + v0 + v1;
  cursor[4 * t + 3] = base + v0 + v1 + v2;
}

// ---------------------------------------------------------------------------
// Prep 4: scatter to Morton-sorted packed SoA: gxyz[dst] = (x,y,z,bits(orig)).
// ---------------------------------------------------------------------------
__global__ void __launch_bounds__(256) prep_scatter_kernel(const float* __restrict__ pos,
                                                           const int* __restrict__ cellid,
                                                           int* __restrict__ cursor,
                                                           float4* __restrict__ gxyz) {
  const int p = blockIdx.x * 256 + threadIdx.x;
  const int c = cellid[p];
  const int dst = atomicAdd(&cursor[c], 1);
  gxyz[dst] = make_float4(pos[3 * p + 0], pos[3 * p + 1], pos[3 * p + 2],
                          __int_as_float(p));
}

// ---------------------------------------------------------------------------
// Prep 5: per-bucket bbox. Bucket = fixed 32-point chunk of sorted order.
// One 64-thread block handles 2 buckets (shfl_xor within 32-lane halves).
// ---------------------------------------------------------------------------
__global__ void __launch_bounds__(64) prep_bktbox_kernel(const float4* __restrict__ gxyz,
                                                         float* __restrict__ gbox) {
  const int lane = threadIdx.x;
  const float4 q = gxyz[blockIdx.x * 64 + lane];
  float mnx = q.x, mxx = q.x, mny = q.y, mxy = q.y, mnz = q.z, mxz = q.z;
#pragma unroll
  for (int off = 16; off > 0; off >>= 1) {
    mnx = fminf(mnx, __shfl_xor(mnx, off)); mxx = fmaxf(mxx, __shfl_xor(mxx, off));
    mny = fminf(mny, __shfl_xor(mny, off)); mxy = fmaxf(mxy, __shfl_xor(mxy, off));
    mnz = fminf(mnz, __shfl_xor(mnz, off)); mxz = fmaxf(mxz, __shfl_xor(mxz, off));
  }
  if ((lane & 31) == 0) {
    const int b = blockIdx.x * 2 + (lane >> 5);
    gbox[b * 8 + 0] = mnx; gbox[b * 8 + 1] = mxx;
    gbox[b * 8 + 2] = mny; gbox[b * 8 + 3] = mxy;
    gbox[b * 8 + 4] = mnz; gbox[b * 8 + 5] = mxz;
    gbox[b * 8 + 6] = 0.0f; gbox[b * 8 + 7] = 0.0f;
  }
}

// ---------------------------------------------------------------------------
// FPS v21 = v18 VERBATIM (measured best: FPS 5175us, total 5397us, absmax 0).
// Reverted from v20 (top-2 cache regressed: Phase B is the critical path;
// +20 u64-ops there cost +870us while the removed Phase-C tail loads had
// slack). Evidence ledger: v16 worklist redistribution -36%; v18 pairing
// -12%; v17 C-tail latency cut = neutral; v19 4-wave = -43%; v20 B-side
// cache = -17%. 512 threads / 8 waves; 2 barriers/round; worklist
// redistribution at point granularity; pair selection via exact runner-up
// test (d2(R,A) >= md_R, packed-key ties).
// ---------------------------------------------------------------------------
__global__ void __launch_bounds__(512) fps_bucket_kernel(
    const float* __restrict__ pos, const float4* __restrict__ gxyz,
    const float* __restrict__ gbox,
    int* __restrict__ idx_out, float* __restrict__ pos_s_out,
    float* __restrict__ batch_s_out) {
  __shared__ float s_md[N_PTS];               // 64 KB running min-dist
  __shared__ unsigned long long s_pk[NBKT];   // 4 KB per-bucket cached argmax
  __shared__ float4 s_wxyz[NBKT];             // 8 KB per-bucket winner coords
  __shared__ int s_wl[NBKT];                  // 2 KB worklist
  __shared__ int s_cnt[2];                    // parity worklist counters
  __shared__ int s_sidx[M_CTR];               // 16 KB selected centers
  const int tid = threadIdx.x;
  const int lane = tid & 63, wave = tid >> 6;

  // init
  for (int i = tid; i < N_PTS; i += 512) s_md[i] = INFINITY;
  // own-bucket bbox in registers (thread t owns bucket t)
  const float bx0 = gbox[tid * 8 + 0], bx1 = gbox[tid * 8 + 1];
  const float by0 = gbox[tid * 8 + 2], by1 = gbox[tid * 8 + 3];
  const float bz0 = gbox[tid * 8 + 4], bz1 = gbox[tid * 8 + 5];
  unsigned long long mpk = ((unsigned long long)0x7f800000u << 32);  // md=+inf
  s_pk[tid] = mpk;
  if (tid < 2) s_cnt[tid] = 0;

  float cxA = pos[0], cyA = pos[1], czA = pos[2];
  int idA = 0;
  float cxB = 0.0f, cyB = 0.0f, czB = 0.0f;
  int idB = 0;
  bool dual = false;
  int t = 0, rc = 0;
  __syncthreads();

  while (true) {
    if (tid == 0) s_sidx[t] = idA;
    ++t;
    if (t >= M_CTR) break;
    if (dual) {
      if (tid == 0) s_sidx[t] = idB;
      ++t;
      if (t >= M_CTR) break;
    }
    const int par = rc & 1;
    ++rc;

    // ---- Phase A: prune (union of balls when dual) + compaction ----
    const float rMax = __uint_as_float((unsigned)(mpk >> 32));
    float dxl = fmaxf(fmaxf(bx0 - cxA, cxA - bx1), 0.0f);
    float dyl = fmaxf(fmaxf(by0 - cyA, cyA - by1), 0.0f);
    float dzl = fmaxf(fmaxf(bz0 - czA, czA - bz1), 0.0f);
    bool flag = (dxl * dxl + dyl * dyl + dzl * dzl) * 0.99999f < rMax;
    if (dual) {
      float ex = fmaxf(fmaxf(bx0 - cxB, cxB - bx1), 0.0f);
      float ey = fmaxf(fmaxf(by0 - cyB, cyB - by1), 0.0f);
      float ez = fmaxf(fmaxf(bz0 - czB, czB - bz1), 0.0f);
      flag = flag || ((ex * ex + ey * ey + ez * ez) * 0.99999f < rMax);
    }
    const unsigned long long ball = __ballot(flag);
    int base = 0;
    if (lane == 0) base = atomicAdd(&s_cnt[par], __popcll(ball));
    base = __builtin_amdgcn_readfirstlane(base);
    if (flag) {
      const int pre = __popcll(ball & ((1ull << lane) - 1ull));
      s_wl[base + pre] = tid;
    }
    __syncthreads();  // bar1: worklist + count ready
    if (tid == 0) s_cnt[par ^ 1] = 0;  // reset other parity (ordered by bar2)

    // ---- Phase B: process flagged buckets at point granularity ----
    const int nf = s_cnt[par];
    const int total = nf << 5;
    for (int bi = 0; bi < total; bi += 512) {
      const int idx = bi + tid;
      if (idx < total) {  // 32-aligned groups are uniformly on/off
        const int b = s_wl[idx >> 5];
        const int p = (b << 5) | (idx & 31);
        const float4 q = gxyz[p];  // coalesced 512B per group, L1/L2 hit
        float nmd = fminf(s_md[p], d2_exact(q.x, q.y, q.z, cxA, cyA, czA));
        if (dual) nmd = fminf(nmd, d2_exact(q.x, q.y, q.z, cxB, cyB, czB));
        s_md[p] = nmd;
        const unsigned long long own =
            ((unsigned long long)__float_as_uint(nmd) << 32) |
            ((unsigned long long)(16383u - (unsigned)__float_as_int(q.w)) << 14) |
            (unsigned)p;
        const unsigned long long red = bucket_bfly_max_u64(own);
        if (own == red) {  // unique winner lane (pk embeds posn)
          s_pk[b] = red;
          s_wxyz[b] = make_float4(q.x, q.y, q.z, 0.0f);
        }
      }
    }
    __syncthreads();  // bar2: s_pk/s_wxyz/s_md fully updated

    // ---- Phase C: replicated global argmax -> A ----
    unsigned long long vv[8];
    unsigned long long loc = 0ULL;
#pragma unroll
    for (int k = 0; k < 8; ++k) {
      const unsigned long long u = s_pk[(k << 6) | lane];
      vv[k] = u;
      if (k == wave) mpk = u;  // own bucket's cache for next Phase A
      if (u > loc) loc = u;
    }
    const unsigned long long bpk = wave_max_u64(loc);
    idA = 16383 - (int)((bpk >> 14) & 16383u);
    const int posn1 = (int)(bpk & 16383u);
    const int b1 = posn1 >> 5;
    {
      const float4 cq = s_wxyz[b1];  // broadcast LDS read
      cxA = cq.x; cyA = cq.y; czA = cq.z;
    }

    // ---- runner-up R + pair test (register re-pass, no extra barrier) ----
    unsigned long long loc2 = 0ULL;
#pragma unroll
    for (int k = 0; k < 8; ++k) {
      const int bb = (k << 6) | lane;
      const unsigned long long u = (bb == b1) ? 0ULL : vv[k];
      if (u > loc2) loc2 = u;
    }
    // intra-bucket-b1 slot pks (A's slot masked); both wave halves duplicate
    const int pp = (b1 << 5) | (lane & 31);
    const float mdv = s_md[pp];
    const float4 qq = gxyz[pp];  // coalesced 512B
    unsigned long long spk =
        ((unsigned long long)__float_as_uint(mdv) << 32) |
        ((unsigned long long)(16383u - (unsigned)__float_as_int(qq.w)) << 14) |
        (unsigned)pp;
    if (pp == posn1) spk = 0ULL;
    if (spk > loc2) loc2 = spk;
    const unsigned long long Rpk = wave_max_u64(loc2);
    const unsigned hiR = (unsigned)(Rpk >> 32);
    const int posnR = (int)(Rpk & 16383u);
    float rx, ry, rz;
    if ((posnR >> 5) == b1) {  // wave-uniform branch
      const int ln = posnR & 31;
      rx = readlane_f(qq.x, ln);
      ry = readlane_f(qq.y, ln);
      rz = readlane_f(qq.z, ln);
    } else {
      const float4 w = s_wxyz[posnR >> 5];
      rx = w.x; ry = w.y; rz = w.z;
    }
    const float dAR = d2_exact(rx, ry, rz, cxA, cyA, czA);
    dual = (hiR != 0u) && (dAR >= __uint_as_float(hiR));
    if (dual) {
      cxB = rx; cyB = ry; czB = rz;
      idB = 16383 - (int)((Rpk >> 14) & 16383u);
    }
  }
  __syncthreads();
  for (int i = tid; i < M_CTR; i += 512) {
    const int si = s_sidx[i];
    idx_out[i] = si;
    pos_s_out[3 * i + 0] = pos[3 * si + 0];  // exact gather == pos[idx]
    pos_s_out[3 * i + 1] = pos[3 * si + 1];
    pos_s_out[3 * i + 2] = pos[3 * si + 2];
    batch_s_out[i] = 0.0f;
  }
}

// ---------------------------------------------------------------------------
// Kernel 2: radius neighbors (unchanged).
// ---------------------------------------------------------------------------
__global__ void __launch_bounds__(256) nbr_kernel(const float* __restrict__ pos,
                                                  const int* __restrict__ idx,
                                                  int* __restrict__ nbr) {
  const int m = blockIdx.x, tid = threadIdx.x;
  __shared__ int s_cnt;
  __shared__ float s_d2[CAP];
  __shared__ int s_idx[CAP];
  if (tid == 0) s_cnt = 0;
  const int cen = idx[m];
  const float cx = pos[3 * cen + 0], cy = pos[3 * cen + 1], cz = pos[3 * cen + 2];
  __syncthreads();
  const float RR = 0.04f;  // f32(python 0.2*0.2)
  for (int i = 0; i < N_PTS / 256; ++i) {
    const int p = tid + 256 * i;
    float d2 = d2_exact(pos[3 * p], pos[3 * p + 1], pos[3 * p + 2], cx, cy, cz);
    if (d2 <= RR) {
      int slot = atomicAdd(&s_cnt, 1);
      if (slot < CAP) { s_d2[slot] = d2; s_idx[slot] = p; }
    }
  }
  __syncthreads();
  const int cnt = s_cnt;
  if (cnt <= K_NBR) {
    if (tid < K_NBR) nbr[m * K_NBR + tid] = (tid < cnt) ? s_idx[tid] : cen;
  } else {
    const int n = cnt < CAP ? cnt : CAP;
    if (tid >= n) { s_d2[tid] = INFINITY; s_idx[tid] = 0x7fffffff; }
    __syncthreads();
    for (int k = 2; k <= CAP; k <<= 1) {
      for (int j = k >> 1; j > 0; j >>= 1) {
        const int ixj = tid ^ j;
        if (ixj > tid) {
          float da = s_d2[tid], db = s_d2[ixj];
          int ia = s_idx[tid], ib = s_idx[ixj];
          bool gt = (da > db) || (da == db && ia > ib);
          bool asc = ((tid & k) == 0);
          if (gt == asc) {
            s_d2[tid] = db; s_d2[ixj] = da;
            s_idx[tid] = ib; s_idx[ixj] = ia;
          }
        }
        __syncthreads();
      }
    }
    if (tid < K_NBR) nbr[m * K_NBR + tid] = s_idx[tid];
  }
}

// ---------------------------------------------------------------------------
// Kernel 3: fused gather + 3-layer MLP + max aggregation (unchanged).
// ---------------------------------------------------------------------------
__device__ __forceinline__ void mlp_layer(const float (*__restrict__ A)[FS],
                                          const float (*__restrict__ W)[64],
                                          int K, int e0, int c0, float acc[4][4]) {
#pragma unroll
  for (int j = 0; j < 4; ++j)
#pragma unroll
    for (int i = 0; i < 4; ++i) acc[j][i] = W[67][c0 + i];  // bias row
#pragma unroll 4
  for (int k = 0; k < K; ++k) {
    const float4 w = *(const float4*)&W[k][c0];
    const float a0 = A[e0 + 0][k], a1 = A[e0 + 1][k];
    const float a2 = A[e0 + 2][k], a3 = A[e0 + 3][k];
    acc[0][0] = fmaf(a0, w.x, acc[0][0]); acc[0][1] = fmaf(a0, w.y, acc[0][1]);
    acc[0][2] = fmaf(a0, w.z, acc[0][2]); acc[0][3] = fmaf(a0, w.w, acc[0][3]);
    acc[1][0] = fmaf(a1, w.x, acc[1][0]); acc[1][1] = fmaf(a1, w.y, acc[1][1]);
    acc[1][2] = fmaf(a1, w.z, acc[1][2]); acc[1][3] = fmaf(a1, w.w, acc[1][3]);
    acc[2][0] = fmaf(a2, w.x, acc[2][0]); acc[2][1] = fmaf(a2, w.y, acc[2][1]);
    acc[2][2] = fmaf(a2, w.z, acc[2][2]); acc[2][3] = fmaf(a2, w.w, acc[2][3]);
    acc[3][0] = fmaf(a3, w.x, acc[3][0]); acc[3][1] = fmaf(a3, w.y, acc[3][1]);
    acc[3][2] = fmaf(a3, w.z, acc[3][2]); acc[3][3] = fmaf(a3, w.w, acc[3][3]);
  }
#pragma unroll
  for (int j = 0; j < 4; ++j)
#pragma unroll
    for (int i = 0; i < 4; ++i) acc[j][i] = fmaxf(acc[j][i], 0.0f);
}

__global__ void __launch_bounds__(512) mlp_kernel(
    const float* __restrict__ x, const float* __restrict__ pos,
    const int* __restrict__ nbr, const float* __restrict__ pos_s,
    const float* __restrict__ W1, const float* __restrict__ b1,
    const float* __restrict__ W2, const float* __restrict__ b2,
    const float* __restrict__ W3, const float* __restrict__ b3,
    float* __restrict__ out) {
  __shared__ float Fb[2][64][FS];
  __shared__ float Wb[FS][64];
  __shared__ float Pb[2][16][64];
  __shared__ int s_nbr[128];
  const int t = threadIdx.x;
  const int m0 = blockIdx.x * 2;

  if (t < 128) s_nbr[t] = nbr[m0 * K_NBR + t];
  __syncthreads();

  {
    const int ge = t >> 2, wch = ge >> 6, e = ge & 63, c16 = (t & 3) * 16;
    const int n = s_nbr[ge];
    const float4* src = (const float4*)(x + n * 64 + c16);
    float4* dst = (float4*)(&Fb[wch][e][c16]);
    dst[0] = src[0]; dst[1] = src[1]; dst[2] = src[2]; dst[3] = src[3];
  }
  if (t < 128) {
    const int wch = t >> 6, e = t & 63;
    const int n = s_nbr[t];
    const float cx = pos_s[(m0 + wch) * 3 + 0];
    const float cy = pos_s[(m0 + wch) * 3 + 1];
    const float cz = pos_s[(m0 + wch) * 3 + 2];
    Fb[wch][e][64] = pos[3 * n + 0] - cx;
    Fb[wch][e][65] = pos[3 * n + 1] - cy;
    Fb[wch][e][66] = pos[3 * n + 2] - cz;
    Fb[wch][e][67] = 0.0f;
  }
  for (int i = t; i < 67 * 64; i += 512) ((float*)Wb)[i] = W1[i];
  if (t < 64) Wb[67][t] = b1[t];
  __syncthreads();

  const int wch = t >> 8, tt = t & 255;
  const int e0 = (tt >> 4) << 2, c0 = (tt & 15) << 2;
  float acc[4][4];

  mlp_layer(Fb[wch], Wb, 67, e0, c0, acc);
  __syncthreads();
#pragma unroll
  for (int j = 0; j < 4; ++j)
#pragma unroll
    for (int i = 0; i < 4; ++i) Fb[wch][e0 + j][c0 + i] = acc[j][i];
  for (int i = t; i < 64 * 64; i += 512) ((float*)Wb)[i] = W2[i];
  if (t < 64) Wb[67][t] = b2[t];
  __syncthreads();

  mlp_layer(Fb[wch], Wb, 64, e0, c0, acc);
  __syncthreads();
#pragma unroll
  for (int j = 0; j < 4; ++j)
#pragma unroll
    for (int i = 0; i < 4; ++i) Fb[wch][e0 + j][c0 + i] = acc[j][i];

  for (int h = 0; h < 2; ++h) {
    for (int i = t; i < 64 * 64; i += 512)
      ((float*)Wb)[i] = W3[(i >> 6) * 128 + h * 64 + (i & 63)];
    if (t < 64) Wb[67][t] = b3[h * 64 + t];
    __syncthreads();
    mlp_layer(Fb[wch], Wb, 64, e0, c0, acc);
#pragma unroll
    for (int i = 0; i < 4; ++i) {
      float v = fmaxf(fmaxf(acc[0][i], acc[1][i]), fmaxf(acc[2][i], acc[3][i]));
      Pb[wch][tt >> 4][c0 + i] = v;
    }
    __syncthreads();
    if (tt < 64) {
      float v = Pb[wch][0][tt];
#pragma unroll
      for (int r = 1; r < 16; ++r) v = fmaxf(v, Pb[wch][r][tt]);
      out[(m0 + wch) * F_OUT + h * 64 + tt] = v;
    }
    __syncthreads();
  }
}

// ---------------------------------------------------------------------------
extern "C" void kernel_launch(void* const* d_in, const int* in_sizes, int n_in,
                              void* d_out, int out_size, void* d_ws, size_t ws_size,
                              hipStream_t stream) {
  const float* x   = (const float*)d_in[0];
  const float* pos = (const float*)d_in[1];
  const float* W1 = (const float*)d_in[3];
  const float* b1 = (const float*)d_in[4];
  const float* W2 = (const float*)d_in[5];
  const float* b2 = (const float*)d_in[6];
  const float* W3 = (const float*)d_in[7];
  const float* b3 = (const float*)d_in[8];

  float* out     = (float*)d_out;                 // [M,128]
  float* pos_s   = out + M_CTR * F_OUT;           // [M,3]
  float* batch_s = pos_s + M_CTR * 3;             // [M]

  // workspace layout (gxyz offset 16B-aligned)
  int*    idx    = (int*)d_ws;                    // 4096
  int*    nbr    = idx + M_CTR;                   // 4096*64
  float*  bbox   = (float*)(nbr + M_CTR * K_NBR); // 8
  int*    hist   = (int*)(bbox + 8);              // 4096
  int*    cursor = hist + NCELL;                  // 4096
  int*    cellid = cursor + NCELL;                // 16384
  float4* gxyz   = (float4*)(cellid + N_PTS);     // 16384 float4
  // gbox (512 buckets x 8 floats = 16 KB) aliases hist: hist is dead after
  // prep_scan, and prep_bktbox runs strictly after it on the same stream.
  float*  gbox   = (float*)hist;

  prep_bbox_kernel<<<1, 1024, 0, stream>>>(pos, bbox, hist);
  prep_cell_kernel<<<N_PTS / 256, 256, 0, stream>>>(pos, bbox, cellid, hist);
  prep_scan_kernel<<<1, 1024, 0, stream>>>(hist, cursor);
  prep_scatter_kernel<<<N_PTS / 256, 256, 0, stream>>>(pos, cellid, cursor, gxyz);
  prep_bktbox_kernel<<<NBKT / 2, 64, 0, stream>>>(gxyz, gbox);
  fps_bucket_kernel<<<1, 512, 0, stream>>>(pos, gxyz, gbox, idx, pos_s, batch_s);
  nbr_kernel<<<M_CTR, 256, 0, stream>>>(pos, idx, nbr);
  mlp_kernel<<<M_CTR / 2, 512, 0, stream>>>(x, pos, nbr, pos_s,
                                            W1, b1, W2, b2, W3, b3, out);
}